// Round 1
// baseline (1453.393 us; speedup 1.0000x reference)
//
#include <hip/hip_runtime.h>

#define H 20
#define Q 32
#define D 64
#define NSTATE 1280
#define CACHE_N 16384
#define NSPLIT 16
#define KCHUNK (CACHE_N / NSPLIT)   // 1024
#define TK 128

// ---------------------------------------------------------------------------
// Tiled GEMM: out[32,1280] (+)= x[32,1280] @ W[1280,1280]^T  (+ bias)
// grid.x = col-block (64 cols each, 20), grid.y = k-split (4), [grid.z = mat]
// Accumulates with atomicAdd into a zeroed output. Bias added by ksplit 0.
// ---------------------------------------------------------------------------
__device__ __forceinline__ void gemm_body(const float* __restrict__ x,
                                          const float* __restrict__ W,
                                          const float* __restrict__ bias,
                                          float* __restrict__ out,
                                          int c0, int ksplit) {
    __shared__ float xs[64][36];   // x^T tile: xs[kk][row]
    __shared__ float ws[64][66];   // W^T tile: ws[kk][col]
    const int t = threadIdx.x;
    const int rt = t >> 5;         // 0..7  -> rows rt*4..rt*4+3
    const int ct = t & 31;         // 0..31 -> cols ct*2..ct*2+1
    float acc[4][2] = {};

    const int kbeg = ksplit * 320;
    for (int k0 = kbeg; k0 < kbeg + 320; k0 += 64) {
        __syncthreads();
        // stage x tile (32 rows x 64 k) transposed
        for (int p = 0; p < 2; ++p) {
            int idx = t + p * 256;
            int row = idx >> 4, c4 = idx & 15;
            float4 v4 = *(const float4*)(x + row * NSTATE + k0 + c4 * 4);
            xs[c4 * 4 + 0][row] = v4.x; xs[c4 * 4 + 1][row] = v4.y;
            xs[c4 * 4 + 2][row] = v4.z; xs[c4 * 4 + 3][row] = v4.w;
        }
        // stage W tile (64 cols x 64 k) transposed
        for (int p = 0; p < 4; ++p) {
            int idx = t + p * 256;
            int c = idx >> 4, c4 = idx & 15;
            float4 v4 = *(const float4*)(W + (long long)(c0 + c) * NSTATE + k0 + c4 * 4);
            ws[c4 * 4 + 0][c] = v4.x; ws[c4 * 4 + 1][c] = v4.y;
            ws[c4 * 4 + 2][c] = v4.z; ws[c4 * 4 + 3][c] = v4.w;
        }
        __syncthreads();
        for (int kk = 0; kk < 64; ++kk) {
            float4 xv = *(const float4*)&xs[kk][rt * 4];
            float2 wv = *(const float2*)&ws[kk][ct * 2];
            acc[0][0] += xv.x * wv.x; acc[0][1] += xv.x * wv.y;
            acc[1][0] += xv.y * wv.x; acc[1][1] += xv.y * wv.y;
            acc[2][0] += xv.z * wv.x; acc[2][1] += xv.z * wv.y;
            acc[3][0] += xv.w * wv.x; acc[3][1] += xv.w * wv.y;
        }
    }
    for (int r = 0; r < 4; ++r) {
        int i = rt * 4 + r;
        for (int cc = 0; cc < 2; ++cc) {
            int c = c0 + ct * 2 + cc;
            float val = acc[r][cc];
            if (ksplit == 0 && bias) val += bias[c];
            atomicAdd(&out[i * NSTATE + c], val);
        }
    }
}

__global__ __launch_bounds__(256)
void gemm_qkv(const float* __restrict__ x,
              const float* __restrict__ Wq, const float* __restrict__ bq,
              const float* __restrict__ Wk,
              const float* __restrict__ Wv, const float* __restrict__ bv,
              float* __restrict__ q, float* __restrict__ k, float* __restrict__ v) {
    const int mat = blockIdx.z;
    const float* W; const float* bias; float* out;
    if (mat == 0)      { W = Wq; bias = bq;      out = q; }
    else if (mat == 1) { W = Wk; bias = nullptr; out = k; }
    else               { W = Wv; bias = bv;      out = v; }
    gemm_body(x, W, bias, out, blockIdx.x * 64, blockIdx.y);
}

__global__ __launch_bounds__(256)
void gemm_one(const float* __restrict__ x, const float* __restrict__ W,
              const float* __restrict__ bias, float* __restrict__ out) {
    gemm_body(x, W, bias, out, blockIdx.x * 64, blockIdx.y);
}

// ---------------------------------------------------------------------------
// Bulk cache copy: d_in caches -> d_out kc/vc regions (float4 grid-stride)
// ---------------------------------------------------------------------------
__global__ void copy_cache(const float4* __restrict__ kin, const float4* __restrict__ vin,
                           float4* __restrict__ kout, float4* __restrict__ vout) {
    const int n = CACHE_N * NSTATE / 4;  // 5,242,880 float4 per tensor
    int i = blockIdx.x * blockDim.x + threadIdx.x;
    int stride = gridDim.x * blockDim.x;
    for (; i < n; i += stride) {
        kout[i] = kin[i];
        vout[i] = vin[i];
    }
}

// Scatter the 32 freshly-projected k/v rows into the caches at `positions`.
__global__ void scatter_rows(const int* __restrict__ pos,
                             const float* __restrict__ k, const float* __restrict__ v,
                             float* __restrict__ kc, float* __restrict__ vc) {
    const int i = blockIdx.x;          // 0..31 (ctx row)
    const int p = pos[i];
    const float4* src;
    float4* dst;
    if (blockIdx.y == 0) { src = (const float4*)(k + i * NSTATE); dst = (float4*)(kc + (long long)p * NSTATE); }
    else                 { src = (const float4*)(v + i * NSTATE); dst = (float4*)(vc + (long long)p * NSTATE); }
    for (int c = threadIdx.x; c < NSTATE / 4; c += blockDim.x) dst[c] = src[c];
}

// ---------------------------------------------------------------------------
// Flash-decoding attention partials: grid (NSPLIT, H), 256 threads.
// Per block: online softmax over its KCHUNK keys for all 32 queries of head h.
// ---------------------------------------------------------------------------
__global__ __launch_bounds__(256)
void attn_partial(const float* __restrict__ qw, const float* __restrict__ kc,
                  const float* __restrict__ vc, const float* __restrict__ mask,
                  float* __restrict__ mpart, float* __restrict__ lpart,
                  float* __restrict__ opart) {
    const int h  = blockIdx.y;
    const int sp = blockIdx.x;
    const int j_base = sp * KCHUNK;

    __shared__ float qs[D][36];       // q^T (scaled): qs[d][i]
    __shared__ float ks_[D][132];     // K^T tile: ks_[d][j]
    __shared__ float vs[TK][68];      // V tile:   vs[j][d]
    __shared__ float ps[TK][36];      // P^T tile: ps[j][i]
    __shared__ float m_s[Q], l_s[Q], alpha_s[Q], tmax[Q], tsum[Q];

    const int t = threadIdx.x;
    const int qt = t >> 5;            // 0..7 : 4 queries each
    const int kt = t & 31;            // 0..31: 4 keys each (score stage)
    const int dt = t & 31;            // 0..31: 2 dims each (PV stage)

    // load q for this head, fold in scale = HEAD_DIM^-0.5 = 1/8
    for (int p = 0; p < 2; ++p) {
        int idx = t + p * 256;
        int i = idx >> 4, c4 = idx & 15;
        float4 v4 = *(const float4*)(qw + i * NSTATE + h * D + c4 * 4);
        const float sc = 0.125f;
        qs[c4 * 4 + 0][i] = v4.x * sc; qs[c4 * 4 + 1][i] = v4.y * sc;
        qs[c4 * 4 + 2][i] = v4.z * sc; qs[c4 * 4 + 3][i] = v4.w * sc;
    }
    if (t < Q) { m_s[t] = -1e30f; l_s[t] = 0.f; }

    float oacc[4][2] = {};            // 4 queries x 2 dims
    __syncthreads();

    for (int tile = 0; tile < KCHUNK / TK; ++tile) {
        const int j0 = j_base + tile * TK;
        __syncthreads();   // protect LDS from previous tile's readers
        // stage K tile transposed
        for (int p = 0; p < 8; ++p) {
            int idx = t + p * 256;
            int row = idx >> 4, c4 = idx & 15;
            float4 v4 = *(const float4*)(kc + (long long)(j0 + row) * NSTATE + h * D + c4 * 4);
            ks_[c4 * 4 + 0][row] = v4.x; ks_[c4 * 4 + 1][row] = v4.y;
            ks_[c4 * 4 + 2][row] = v4.z; ks_[c4 * 4 + 3][row] = v4.w;
        }
        // stage V tile
        for (int p = 0; p < 8; ++p) {
            int idx = t + p * 256;
            int row = idx >> 4, c4 = idx & 15;
            *(float4*)&vs[row][c4 * 4] =
                *(const float4*)(vc + (long long)(j0 + row) * NSTATE + h * D + c4 * 4);
        }
        __syncthreads();

        // QK^T: 4q x 4k per thread
        float s[4][4] = {};
        for (int d = 0; d < D; ++d) {
            float4 qv = *(const float4*)&qs[d][qt * 4];
            float4 kv = *(const float4*)&ks_[d][kt * 4];
            s[0][0] += qv.x * kv.x; s[0][1] += qv.x * kv.y; s[0][2] += qv.x * kv.z; s[0][3] += qv.x * kv.w;
            s[1][0] += qv.y * kv.x; s[1][1] += qv.y * kv.y; s[1][2] += qv.y * kv.z; s[1][3] += qv.y * kv.w;
            s[2][0] += qv.z * kv.x; s[2][1] += qv.z * kv.y; s[2][2] += qv.z * kv.z; s[2][3] += qv.z * kv.w;
            s[3][0] += qv.w * kv.x; s[3][1] += qv.w * kv.y; s[3][2] += qv.w * kv.z; s[3][3] += qv.w * kv.w;
        }
        // + mask
        for (int r = 0; r < 4; ++r) {
            int i = qt * 4 + r;
            float4 mv = *(const float4*)(mask + (long long)i * CACHE_N + j0 + kt * 4);
            s[r][0] += mv.x; s[r][1] += mv.y; s[r][2] += mv.z; s[r][3] += mv.w;
        }
        // per-query tile max (reduce over this thread's 4 keys, then 32 kt lanes)
        float rmax[4];
        for (int r = 0; r < 4; ++r)
            rmax[r] = fmaxf(fmaxf(s[r][0], s[r][1]), fmaxf(s[r][2], s[r][3]));
        for (int off = 16; off >= 1; off >>= 1)
            for (int r = 0; r < 4; ++r)
                rmax[r] = fmaxf(rmax[r], __shfl_xor(rmax[r], off, 64));
        if (kt == 0)
            for (int r = 0; r < 4; ++r) tmax[qt * 4 + r] = rmax[r];
        __syncthreads();
        if (t < Q) {
            float mo = m_s[t], mn = fmaxf(mo, tmax[t]);
            float a = __expf(mo - mn);
            m_s[t] = mn; alpha_s[t] = a; l_s[t] *= a;
        }
        __syncthreads();
        // p = exp(s - m_new); write P^T tile; per-query row sums
        float pr[4][4];
        float rsum[4];
        for (int r = 0; r < 4; ++r) {
            int i = qt * 4 + r;
            float mn = m_s[i];
            pr[r][0] = __expf(s[r][0] - mn); pr[r][1] = __expf(s[r][1] - mn);
            pr[r][2] = __expf(s[r][2] - mn); pr[r][3] = __expf(s[r][3] - mn);
            rsum[r] = pr[r][0] + pr[r][1] + pr[r][2] + pr[r][3];
        }
        for (int c = 0; c < 4; ++c) {
            float4 w4 = make_float4(pr[0][c], pr[1][c], pr[2][c], pr[3][c]);
            *(float4*)&ps[kt * 4 + c][qt * 4] = w4;
        }
        for (int off = 16; off >= 1; off >>= 1)
            for (int r = 0; r < 4; ++r)
                rsum[r] += __shfl_xor(rsum[r], off, 64);
        if (kt == 0)
            for (int r = 0; r < 4; ++r) tsum[qt * 4 + r] = rsum[r];
        // rescale running output
        {
            float a0 = alpha_s[qt * 4 + 0], a1 = alpha_s[qt * 4 + 1];
            float a2 = alpha_s[qt * 4 + 2], a3 = alpha_s[qt * 4 + 3];
            oacc[0][0] *= a0; oacc[0][1] *= a0;
            oacc[1][0] *= a1; oacc[1][1] *= a1;
            oacc[2][0] *= a2; oacc[2][1] *= a2;
            oacc[3][0] *= a3; oacc[3][1] *= a3;
        }
        __syncthreads();
        if (t < Q) l_s[t] += tsum[t];
        // PV: o[i][d] += sum_j p[i][j] * v[j][d]   (4q x 2d per thread)
        for (int j = 0; j < TK; ++j) {
            float4 pv = *(const float4*)&ps[j][qt * 4];
            float2 vv = *(const float2*)&vs[j][dt * 2];
            oacc[0][0] += pv.x * vv.x; oacc[0][1] += pv.x * vv.y;
            oacc[1][0] += pv.y * vv.x; oacc[1][1] += pv.y * vv.y;
            oacc[2][0] += pv.z * vv.x; oacc[2][1] += pv.z * vv.y;
            oacc[3][0] += pv.w * vv.x; oacc[3][1] += pv.w * vv.y;
        }
    }
    __syncthreads();
    const int pb = (h * NSPLIT + sp) * Q;
    if (t < Q) { mpart[pb + t] = m_s[t]; lpart[pb + t] = l_s[t]; }
    for (int r = 0; r < 4; ++r) {
        int i = qt * 4 + r;
        *(float2*)&opart[(long long)(pb + i) * D + dt * 2] = make_float2(oacc[r][0], oacc[r][1]);
    }
}

// Combine split partials -> attention output [32,1280]
__global__ __launch_bounds__(64)
void attn_combine(const float* __restrict__ mpart, const float* __restrict__ lpart,
                  const float* __restrict__ opart, float* __restrict__ oattn) {
    const int i = blockIdx.x;   // query
    const int h = blockIdx.y;   // head
    const int d = threadIdx.x;  // dim
    float m[NSPLIT];
    float gm = -1e30f;
    for (int s = 0; s < NSPLIT; ++s) {
        m[s] = mpart[(h * NSPLIT + s) * Q + i];
        gm = fmaxf(gm, m[s]);
    }
    float l = 0.f, o = 0.f;
    for (int s = 0; s < NSPLIT; ++s) {
        float w = __expf(m[s] - gm);
        l += lpart[(h * NSPLIT + s) * Q + i] * w;
        o += opart[(long long)((h * NSPLIT + s) * Q + i) * D + d] * w;
    }
    oattn[i * NSTATE + h * D + d] = o / l;
}

// ---------------------------------------------------------------------------
extern "C" void kernel_launch(void* const* d_in, const int* in_sizes, int n_in,
                              void* d_out, int out_size, void* d_ws, size_t ws_size,
                              hipStream_t stream) {
    const float* x    = (const float*)d_in[0];
    const float* kci  = (const float*)d_in[1];
    const float* vci  = (const float*)d_in[2];
    const int*   pos  = (const int*)d_in[3];
    const float* mask = (const float*)d_in[4];
    const float* Wq   = (const float*)d_in[5];
    const float* bq   = (const float*)d_in[6];
    const float* Wk   = (const float*)d_in[7];
    const float* Wv   = (const float*)d_in[8];
    const float* bv   = (const float*)d_in[9];
    const float* Wout = (const float*)d_in[10];
    const float* bout = (const float*)d_in[11];

    float* out  = (float*)d_out;                 // [32*1280]
    float* kc   = out + 40960;                   // [16384*1280]
    float* vc   = kc + CACHE_N * NSTATE;         // [16384*1280]

    float* ws     = (float*)d_ws;
    float* qws    = ws;                          // 40960
    float* kws    = ws + 40960;                  // 40960
    float* vws    = ws + 81920;                  // 40960
    float* oattn  = ws + 122880;                 // 40960
    float* mpart  = ws + 163840;                 // 10240
    float* lpart  = ws + 174080;                 // 10240
    float* opart  = ws + 184320;                 // 655360

    // zero accumulation targets (atomicAdd GEMMs)
    hipMemsetAsync(qws, 0, 3 * 40960 * sizeof(float), stream);
    hipMemsetAsync(out, 0, 40960 * sizeof(float), stream);

    // 1. q/k/v projections
    gemm_qkv<<<dim3(NSTATE / 64, 4, 3), 256, 0, stream>>>(x, Wq, bq, Wk, Wv, bv, qws, kws, vws);

    // 2. bulk cache copy into d_out
    copy_cache<<<2048, 256, 0, stream>>>((const float4*)kci, (const float4*)vci,
                                         (float4*)kc, (float4*)vc);

    // 3. scatter new rows at positions
    scatter_rows<<<dim3(Q, 2), 320, 0, stream>>>(pos, kws, vws, kc, vc);

    // 4. attention partials (flash-decoding split over keys)
    attn_partial<<<dim3(NSPLIT, H), 256, 0, stream>>>(qws, kc, vc, mask, mpart, lpart, opart);

    // 5. combine
    attn_combine<<<dim3(Q, H), 64, 0, stream>>>(mpart, lpart, opart, oattn);

    // 6. output projection
    gemm_one<<<dim3(NSTATE / 64, 4), 256, 0, stream>>>(oattn, Wout, bout, out);
}

// Round 2
// 505.358 us; speedup vs baseline: 2.8760x; 2.8760x over previous
//
#include <hip/hip_runtime.h>

#define H 20
#define Q 32
#define D 64
#define NSTATE 1280
#define CACHE_N 16384
#define NSPLIT 16
#define KCHUNK (CACHE_N / NSPLIT)   // 1024
#define TK 128

// ---------------------------------------------------------------------------
// Tiled GEMM: out[32,1280] (+)= x[32,1280] @ W[1280,1280]^T  (+ bias)
// grid.x = col-block (64 cols each, 20), grid.y = k-split (4), [grid.z = mat]
// Accumulates with atomicAdd into a zeroed output. Bias added by ksplit 0.
// NOTE: unroll pragmas are load-bearing — full unroll of the FMA loops made
// the compiler hoist hundreds of LDS loads, spill past 256 VGPRs, and turn
// this kernel into 1 GB of scratch traffic (653 us, round 1).
// ---------------------------------------------------------------------------
__device__ __forceinline__ void gemm_body(const float* __restrict__ x,
                                          const float* __restrict__ W,
                                          const float* __restrict__ bias,
                                          float* __restrict__ out,
                                          int c0, int ksplit) {
    __shared__ float xs[64][36];   // x^T tile: xs[kk][row]
    __shared__ float ws[64][66];   // W^T tile: ws[kk][col]
    const int t = threadIdx.x;
    const int rt = t >> 5;         // 0..7  -> rows rt*4..rt*4+3
    const int ct = t & 31;         // 0..31 -> cols ct*2..ct*2+1
    float acc[4][2] = {};

    const int kbeg = ksplit * 320;
#pragma unroll 1
    for (int k0 = kbeg; k0 < kbeg + 320; k0 += 64) {
        __syncthreads();
        // stage x tile (32 rows x 64 k) transposed
#pragma unroll
        for (int p = 0; p < 2; ++p) {
            int idx = t + p * 256;
            int row = idx >> 4, c4 = idx & 15;
            float4 v4 = *(const float4*)(x + row * NSTATE + k0 + c4 * 4);
            xs[c4 * 4 + 0][row] = v4.x; xs[c4 * 4 + 1][row] = v4.y;
            xs[c4 * 4 + 2][row] = v4.z; xs[c4 * 4 + 3][row] = v4.w;
        }
        // stage W tile (64 cols x 64 k) transposed
#pragma unroll
        for (int p = 0; p < 4; ++p) {
            int idx = t + p * 256;
            int c = idx >> 4, c4 = idx & 15;
            float4 v4 = *(const float4*)(W + (long long)(c0 + c) * NSTATE + k0 + c4 * 4);
            ws[c4 * 4 + 0][c] = v4.x; ws[c4 * 4 + 1][c] = v4.y;
            ws[c4 * 4 + 2][c] = v4.z; ws[c4 * 4 + 3][c] = v4.w;
        }
        __syncthreads();
#pragma unroll 8
        for (int kk = 0; kk < 64; ++kk) {
            float4 xv = *(const float4*)&xs[kk][rt * 4];
            float2 wv = *(const float2*)&ws[kk][ct * 2];
            acc[0][0] += xv.x * wv.x; acc[0][1] += xv.x * wv.y;
            acc[1][0] += xv.y * wv.x; acc[1][1] += xv.y * wv.y;
            acc[2][0] += xv.z * wv.x; acc[2][1] += xv.z * wv.y;
            acc[3][0] += xv.w * wv.x; acc[3][1] += xv.w * wv.y;
        }
    }
#pragma unroll
    for (int r = 0; r < 4; ++r) {
        int i = rt * 4 + r;
#pragma unroll
        for (int cc = 0; cc < 2; ++cc) {
            int c = c0 + ct * 2 + cc;
            float val = acc[r][cc];
            if (ksplit == 0 && bias) val += bias[c];
            atomicAdd(&out[i * NSTATE + c], val);
        }
    }
}

__global__ __launch_bounds__(256, 2)
void gemm_qkv(const float* __restrict__ x,
              const float* __restrict__ Wq, const float* __restrict__ bq,
              const float* __restrict__ Wk,
              const float* __restrict__ Wv, const float* __restrict__ bv,
              float* __restrict__ q, float* __restrict__ k, float* __restrict__ v) {
    const int mat = blockIdx.z;
    const float* W; const float* bias; float* out;
    if (mat == 0)      { W = Wq; bias = bq;      out = q; }
    else if (mat == 1) { W = Wk; bias = nullptr; out = k; }
    else               { W = Wv; bias = bv;      out = v; }
    gemm_body(x, W, bias, out, blockIdx.x * 64, blockIdx.y);
}

__global__ __launch_bounds__(256, 2)
void gemm_one(const float* __restrict__ x, const float* __restrict__ W,
              const float* __restrict__ bias, float* __restrict__ out) {
    gemm_body(x, W, bias, out, blockIdx.x * 64, blockIdx.y);
}

// ---------------------------------------------------------------------------
// Bulk cache copy: d_in caches -> d_out kc/vc regions (float4 grid-stride)
// ---------------------------------------------------------------------------
__global__ void copy_cache(const float4* __restrict__ kin, const float4* __restrict__ vin,
                           float4* __restrict__ kout, float4* __restrict__ vout) {
    const int n = CACHE_N * NSTATE / 4;  // 5,242,880 float4 per tensor
    int i = blockIdx.x * blockDim.x + threadIdx.x;
    int stride = gridDim.x * blockDim.x;
#pragma unroll 1
    for (; i < n; i += stride) {
        kout[i] = kin[i];
        vout[i] = vin[i];
    }
}

// Scatter the 32 freshly-projected k/v rows into the caches at `positions`.
__global__ void scatter_rows(const int* __restrict__ pos,
                             const float* __restrict__ k, const float* __restrict__ v,
                             float* __restrict__ kc, float* __restrict__ vc) {
    const int i = blockIdx.x;          // 0..31 (ctx row)
    const int p = pos[i];
    const float4* src;
    float4* dst;
    if (blockIdx.y == 0) { src = (const float4*)(k + i * NSTATE); dst = (float4*)(kc + (long long)p * NSTATE); }
    else                 { src = (const float4*)(v + i * NSTATE); dst = (float4*)(vc + (long long)p * NSTATE); }
    for (int c = threadIdx.x; c < NSTATE / 4; c += blockDim.x) dst[c] = src[c];
}

// ---------------------------------------------------------------------------
// Flash-decoding attention partials: grid (NSPLIT, H), 256 threads.
// Per block: online softmax over its KCHUNK keys for all 32 queries of head h.
// ---------------------------------------------------------------------------
__global__ __launch_bounds__(256, 2)
void attn_partial(const float* __restrict__ qw, const float* __restrict__ kc,
                  const float* __restrict__ vc, const float* __restrict__ mask,
                  float* __restrict__ mpart, float* __restrict__ lpart,
                  float* __restrict__ opart) {
    const int h  = blockIdx.y;
    const int sp = blockIdx.x;
    const int j_base = sp * KCHUNK;

    __shared__ float qs[D][36];       // q^T (scaled): qs[d][i]
    __shared__ float ks_[D][132];     // K^T tile: ks_[d][j]
    __shared__ float vs[TK][68];      // V tile:   vs[j][d]
    __shared__ float ps[TK][36];      // P^T tile: ps[j][i]
    __shared__ float m_s[Q], l_s[Q], alpha_s[Q], tmax[Q], tsum[Q];

    const int t = threadIdx.x;
    const int qt = t >> 5;            // 0..7 : 4 queries each
    const int kt = t & 31;            // 0..31: 4 keys each (score stage)
    const int dt = t & 31;            // 0..31: 2 dims each (PV stage)

    // load q for this head, fold in scale = HEAD_DIM^-0.5 = 1/8
#pragma unroll
    for (int p = 0; p < 2; ++p) {
        int idx = t + p * 256;
        int i = idx >> 4, c4 = idx & 15;
        float4 v4 = *(const float4*)(qw + i * NSTATE + h * D + c4 * 4);
        const float sc = 0.125f;
        qs[c4 * 4 + 0][i] = v4.x * sc; qs[c4 * 4 + 1][i] = v4.y * sc;
        qs[c4 * 4 + 2][i] = v4.z * sc; qs[c4 * 4 + 3][i] = v4.w * sc;
    }
    if (t < Q) { m_s[t] = -1e30f; l_s[t] = 0.f; }

    float oacc[4][2] = {};            // 4 queries x 2 dims
    __syncthreads();

#pragma unroll 1
    for (int tile = 0; tile < KCHUNK / TK; ++tile) {
        const int j0 = j_base + tile * TK;
        __syncthreads();   // protect LDS from previous tile's readers
        // stage K tile transposed
#pragma unroll
        for (int p = 0; p < 8; ++p) {
            int idx = t + p * 256;
            int row = idx >> 4, c4 = idx & 15;
            float4 v4 = *(const float4*)(kc + (long long)(j0 + row) * NSTATE + h * D + c4 * 4);
            ks_[c4 * 4 + 0][row] = v4.x; ks_[c4 * 4 + 1][row] = v4.y;
            ks_[c4 * 4 + 2][row] = v4.z; ks_[c4 * 4 + 3][row] = v4.w;
        }
        // stage V tile
#pragma unroll
        for (int p = 0; p < 8; ++p) {
            int idx = t + p * 256;
            int row = idx >> 4, c4 = idx & 15;
            *(float4*)&vs[row][c4 * 4] =
                *(const float4*)(vc + (long long)(j0 + row) * NSTATE + h * D + c4 * 4);
        }
        __syncthreads();

        // QK^T: 4q x 4k per thread
        float s[4][4] = {};
#pragma unroll 8
        for (int d = 0; d < D; ++d) {
            float4 qv = *(const float4*)&qs[d][qt * 4];
            float4 kv = *(const float4*)&ks_[d][kt * 4];
            s[0][0] += qv.x * kv.x; s[0][1] += qv.x * kv.y; s[0][2] += qv.x * kv.z; s[0][3] += qv.x * kv.w;
            s[1][0] += qv.y * kv.x; s[1][1] += qv.y * kv.y; s[1][2] += qv.y * kv.z; s[1][3] += qv.y * kv.w;
            s[2][0] += qv.z * kv.x; s[2][1] += qv.z * kv.y; s[2][2] += qv.z * kv.z; s[2][3] += qv.z * kv.w;
            s[3][0] += qv.w * kv.x; s[3][1] += qv.w * kv.y; s[3][2] += qv.w * kv.z; s[3][3] += qv.w * kv.w;
        }
        // + mask
#pragma unroll
        for (int r = 0; r < 4; ++r) {
            int i = qt * 4 + r;
            float4 mv = *(const float4*)(mask + (long long)i * CACHE_N + j0 + kt * 4);
            s[r][0] += mv.x; s[r][1] += mv.y; s[r][2] += mv.z; s[r][3] += mv.w;
        }
        // per-query tile max (reduce over this thread's 4 keys, then 32 kt lanes)
        float rmax[4];
#pragma unroll
        for (int r = 0; r < 4; ++r)
            rmax[r] = fmaxf(fmaxf(s[r][0], s[r][1]), fmaxf(s[r][2], s[r][3]));
#pragma unroll
        for (int off = 16; off >= 1; off >>= 1)
#pragma unroll
            for (int r = 0; r < 4; ++r)
                rmax[r] = fmaxf(rmax[r], __shfl_xor(rmax[r], off, 64));
        if (kt == 0)
#pragma unroll
            for (int r = 0; r < 4; ++r) tmax[qt * 4 + r] = rmax[r];
        __syncthreads();
        if (t < Q) {
            float mo = m_s[t], mn = fmaxf(mo, tmax[t]);
            float a = __expf(mo - mn);
            m_s[t] = mn; alpha_s[t] = a; l_s[t] *= a;
        }
        __syncthreads();
        // p = exp(s - m_new); write P^T tile; per-query row sums
        float pr[4][4];
        float rsum[4];
#pragma unroll
        for (int r = 0; r < 4; ++r) {
            int i = qt * 4 + r;
            float mn = m_s[i];
            pr[r][0] = __expf(s[r][0] - mn); pr[r][1] = __expf(s[r][1] - mn);
            pr[r][2] = __expf(s[r][2] - mn); pr[r][3] = __expf(s[r][3] - mn);
            rsum[r] = pr[r][0] + pr[r][1] + pr[r][2] + pr[r][3];
        }
#pragma unroll
        for (int c = 0; c < 4; ++c) {
            float4 w4 = make_float4(pr[0][c], pr[1][c], pr[2][c], pr[3][c]);
            *(float4*)&ps[kt * 4 + c][qt * 4] = w4;
        }
#pragma unroll
        for (int off = 16; off >= 1; off >>= 1)
#pragma unroll
            for (int r = 0; r < 4; ++r)
                rsum[r] += __shfl_xor(rsum[r], off, 64);
        if (kt == 0)
#pragma unroll
            for (int r = 0; r < 4; ++r) tsum[qt * 4 + r] = rsum[r];
        // rescale running output
        {
            float a0 = alpha_s[qt * 4 + 0], a1 = alpha_s[qt * 4 + 1];
            float a2 = alpha_s[qt * 4 + 2], a3 = alpha_s[qt * 4 + 3];
            oacc[0][0] *= a0; oacc[0][1] *= a0;
            oacc[1][0] *= a1; oacc[1][1] *= a1;
            oacc[2][0] *= a2; oacc[2][1] *= a2;
            oacc[3][0] *= a3; oacc[3][1] *= a3;
        }
        __syncthreads();
        if (t < Q) l_s[t] += tsum[t];
        // PV: o[i][d] += sum_j p[i][j] * v[j][d]   (4q x 2d per thread)
#pragma unroll 8
        for (int j = 0; j < TK; ++j) {
            float4 pv = *(const float4*)&ps[j][qt * 4];
            float2 vv = *(const float2*)&vs[j][dt * 2];
            oacc[0][0] += pv.x * vv.x; oacc[0][1] += pv.x * vv.y;
            oacc[1][0] += pv.y * vv.x; oacc[1][1] += pv.y * vv.y;
            oacc[2][0] += pv.z * vv.x; oacc[2][1] += pv.z * vv.y;
            oacc[3][0] += pv.w * vv.x; oacc[3][1] += pv.w * vv.y;
        }
    }
    __syncthreads();
    const int pb = (h * NSPLIT + sp) * Q;
    if (t < Q) { mpart[pb + t] = m_s[t]; lpart[pb + t] = l_s[t]; }
#pragma unroll
    for (int r = 0; r < 4; ++r) {
        int i = qt * 4 + r;
        *(float2*)&opart[(long long)(pb + i) * D + dt * 2] = make_float2(oacc[r][0], oacc[r][1]);
    }
}

// Combine split partials -> attention output [32,1280]
__global__ __launch_bounds__(64)
void attn_combine(const float* __restrict__ mpart, const float* __restrict__ lpart,
                  const float* __restrict__ opart, float* __restrict__ oattn) {
    const int i = blockIdx.x;   // query
    const int h = blockIdx.y;   // head
    const int d = threadIdx.x;  // dim
    float m[NSPLIT];
    float gm = -1e30f;
#pragma unroll
    for (int s = 0; s < NSPLIT; ++s) {
        m[s] = mpart[(h * NSPLIT + s) * Q + i];
        gm = fmaxf(gm, m[s]);
    }
    float l = 0.f, o = 0.f;
#pragma unroll
    for (int s = 0; s < NSPLIT; ++s) {
        float w = __expf(m[s] - gm);
        l += lpart[(h * NSPLIT + s) * Q + i] * w;
        o += opart[(long long)((h * NSPLIT + s) * Q + i) * D + d] * w;
    }
    oattn[i * NSTATE + h * D + d] = o / l;
}

// ---------------------------------------------------------------------------
extern "C" void kernel_launch(void* const* d_in, const int* in_sizes, int n_in,
                              void* d_out, int out_size, void* d_ws, size_t ws_size,
                              hipStream_t stream) {
    const float* x    = (const float*)d_in[0];
    const float* kci  = (const float*)d_in[1];
    const float* vci  = (const float*)d_in[2];
    const int*   pos  = (const int*)d_in[3];
    const float* mask = (const float*)d_in[4];
    const float* Wq   = (const float*)d_in[5];
    const float* bq   = (const float*)d_in[6];
    const float* Wk   = (const float*)d_in[7];
    const float* Wv   = (const float*)d_in[8];
    const float* bv   = (const float*)d_in[9];
    const float* Wout = (const float*)d_in[10];
    const float* bout = (const float*)d_in[11];

    float* out  = (float*)d_out;                 // [32*1280]
    float* kc   = out + 40960;                   // [16384*1280]
    float* vc   = kc + CACHE_N * NSTATE;         // [16384*1280]

    float* ws     = (float*)d_ws;
    float* qws    = ws;                          // 40960
    float* kws    = ws + 40960;                  // 40960
    float* vws    = ws + 81920;                  // 40960
    float* oattn  = ws + 122880;                 // 40960
    float* mpart  = ws + 163840;                 // 10240
    float* lpart  = ws + 174080;                 // 10240
    float* opart  = ws + 184320;                 // 655360

    // zero accumulation targets (atomicAdd GEMMs)
    hipMemsetAsync(qws, 0, 3 * 40960 * sizeof(float), stream);
    hipMemsetAsync(out, 0, 40960 * sizeof(float), stream);

    // 1. q/k/v projections
    gemm_qkv<<<dim3(NSTATE / 64, 4, 3), 256, 0, stream>>>(x, Wq, bq, Wk, Wv, bv, qws, kws, vws);

    // 2. bulk cache copy into d_out
    copy_cache<<<2048, 256, 0, stream>>>((const float4*)kci, (const float4*)vci,
                                         (float4*)kc, (float4*)vc);

    // 3. scatter new rows at positions
    scatter_rows<<<dim3(Q, 2), 320, 0, stream>>>(pos, kws, vws, kc, vc);

    // 4. attention partials (flash-decoding split over keys)
    attn_partial<<<dim3(NSPLIT, H), 256, 0, stream>>>(qws, kc, vc, mask, mpart, lpart, opart);

    // 5. combine
    attn_combine<<<dim3(Q, H), 64, 0, stream>>>(mpart, lpart, opart, oattn);

    // 6. output projection
    gemm_one<<<dim3(NSTATE / 64, 4), 256, 0, stream>>>(oattn, Wout, bout, out);
}

// Round 3
// 403.746 us; speedup vs baseline: 3.5998x; 1.2517x over previous
//
#include <hip/hip_runtime.h>
#include <hip/hip_bf16.h>

#define H 20
#define Q 32
#define D 64
#define NSTATE 1280
#define CACHE_N 16384
#define NSPLIT 32
#define KCHUNK (CACHE_N / NSPLIT)   // 512 rows per split
#define TK 64                        // rows per tile

// ---------------------------------------------------------------------------
// Tiled GEMM: out[32,1280] (+)= x[32,1280] @ W[1280,1280]^T  (+ bias)
// grid.x = col-block (64 cols each, 20), grid.y = k-split (4), [grid.z = mat]
// NOTE: unroll pragmas are load-bearing — full unroll spilled past 256 VGPRs
// and generated 1 GB of scratch traffic (653 us) in round 1.
// ---------------------------------------------------------------------------
__device__ __forceinline__ void gemm_body(const float* __restrict__ x,
                                          const float* __restrict__ W,
                                          const float* __restrict__ bias,
                                          float* __restrict__ out,
                                          int c0, int ksplit) {
    __shared__ float xs[64][36];   // x^T tile: xs[kk][row]
    __shared__ float ws[64][66];   // W^T tile: ws[kk][col]
    const int t = threadIdx.x;
    const int rt = t >> 5;         // 0..7  -> rows rt*4..rt*4+3
    const int ct = t & 31;         // 0..31 -> cols ct*2..ct*2+1
    float acc[4][2] = {};

    const int kbeg = ksplit * 320;
#pragma unroll 1
    for (int k0 = kbeg; k0 < kbeg + 320; k0 += 64) {
        __syncthreads();
#pragma unroll
        for (int p = 0; p < 2; ++p) {
            int idx = t + p * 256;
            int row = idx >> 4, c4 = idx & 15;
            float4 v4 = *(const float4*)(x + row * NSTATE + k0 + c4 * 4);
            xs[c4 * 4 + 0][row] = v4.x; xs[c4 * 4 + 1][row] = v4.y;
            xs[c4 * 4 + 2][row] = v4.z; xs[c4 * 4 + 3][row] = v4.w;
        }
#pragma unroll
        for (int p = 0; p < 4; ++p) {
            int idx = t + p * 256;
            int c = idx >> 4, c4 = idx & 15;
            float4 v4 = *(const float4*)(W + (long long)(c0 + c) * NSTATE + k0 + c4 * 4);
            ws[c4 * 4 + 0][c] = v4.x; ws[c4 * 4 + 1][c] = v4.y;
            ws[c4 * 4 + 2][c] = v4.z; ws[c4 * 4 + 3][c] = v4.w;
        }
        __syncthreads();
#pragma unroll 8
        for (int kk = 0; kk < 64; ++kk) {
            float4 xv = *(const float4*)&xs[kk][rt * 4];
            float2 wv = *(const float2*)&ws[kk][ct * 2];
            acc[0][0] += xv.x * wv.x; acc[0][1] += xv.x * wv.y;
            acc[1][0] += xv.y * wv.x; acc[1][1] += xv.y * wv.y;
            acc[2][0] += xv.z * wv.x; acc[2][1] += xv.z * wv.y;
            acc[3][0] += xv.w * wv.x; acc[3][1] += xv.w * wv.y;
        }
    }
#pragma unroll
    for (int r = 0; r < 4; ++r) {
        int i = rt * 4 + r;
#pragma unroll
        for (int cc = 0; cc < 2; ++cc) {
            int c = c0 + ct * 2 + cc;
            float val = acc[r][cc];
            if (ksplit == 0 && bias) val += bias[c];
            atomicAdd(&out[i * NSTATE + c], val);
        }
    }
}

__global__ __launch_bounds__(256, 2)
void gemm_qkv(const float* __restrict__ x,
              const float* __restrict__ Wq, const float* __restrict__ bq,
              const float* __restrict__ Wk,
              const float* __restrict__ Wv, const float* __restrict__ bv,
              float* __restrict__ q, float* __restrict__ k, float* __restrict__ v) {
    const int mat = blockIdx.z;
    const float* W; const float* bias; float* out;
    if (mat == 0)      { W = Wq; bias = bq;      out = q; }
    else if (mat == 1) { W = Wk; bias = nullptr; out = k; }
    else               { W = Wv; bias = bv;      out = v; }
    gemm_body(x, W, bias, out, blockIdx.x * 64, blockIdx.y);
}

__global__ __launch_bounds__(256, 2)
void gemm_one(const float* __restrict__ x, const float* __restrict__ W,
              const float* __restrict__ bias, float* __restrict__ out) {
    gemm_body(x, W, bias, out, blockIdx.x * 64, blockIdx.y);
}

// rowmap[j] = i if positions[i] == j else -1 (rowmap pre-memset to 0xFF)
__global__ void build_rowmap(const int* __restrict__ pos, int* __restrict__ rowmap) {
    int i = threadIdx.x;
    if (i < Q) rowmap[pos[i]] = i;   // duplicate positions: higher i wins (last-set)
}

// ---------------------------------------------------------------------------
// FUSED: cache-update write-through + flash-decoding attention partials.
// grid (NSPLIT, H). Block (sp,h) streams rows [sp*512,(sp+1)*512) x cols
// [h*64,(h+1)*64) of K and V from the input caches (with rowmap replacement
// from the fresh projections), writes them to the output caches, and runs
// QK^T -> online softmax -> PV on the same data. The copy is thus free.
// ---------------------------------------------------------------------------
__global__ __launch_bounds__(256, 2)
void attn_fused(const float* __restrict__ qw,
                const float* __restrict__ kci, const float* __restrict__ vci,
                const float* __restrict__ knew, const float* __restrict__ vnew,
                const int* __restrict__ rowmap, const float* __restrict__ mask,
                float* __restrict__ kc, float* __restrict__ vc,
                float* __restrict__ mpart, float* __restrict__ lpart,
                __hip_bfloat16* __restrict__ opart) {
    const int h  = blockIdx.y;
    const int sp = blockIdx.x;
    const int j_base = sp * KCHUNK;

    __shared__ float qs[D][36];       // q^T (scaled): qs[d][i]
    __shared__ float ks_[D][66];      // K^T tile: ks_[d][j]   (scalar writes, f2 reads)
    __shared__ float vs[TK][68];      // V tile:   vs[j][d]    (f4 writes, f2 reads)
    __shared__ float ps[TK][36];      // P^T tile: ps[j][i]
    __shared__ float m_s[Q], l_s[Q], alpha_s[Q], tmax[Q], tsum[Q];

    const int t = threadIdx.x;
    const int qt = t >> 5;            // 0..7 : 4 queries each
    const int kt = t & 31;            // 0..31: 2 keys each (QK stage)
    const int dt = t & 31;            // 0..31: 2 dims each (PV stage)

    // stage q for this head, fold in scale = 1/sqrt(64) = 0.125
#pragma unroll
    for (int p = 0; p < 2; ++p) {
        int idx = t + p * 256;
        int i = idx >> 4, c4 = idx & 15;
        float4 v4 = *(const float4*)(qw + i * NSTATE + h * D + c4 * 4);
        const float sc = 0.125f;
        qs[c4 * 4 + 0][i] = v4.x * sc; qs[c4 * 4 + 1][i] = v4.y * sc;
        qs[c4 * 4 + 2][i] = v4.z * sc; qs[c4 * 4 + 3][i] = v4.w * sc;
    }
    if (t < Q) { m_s[t] = -1e30f; l_s[t] = 0.f; }
    float oacc[4][2] = {};
    __syncthreads();

#pragma unroll 1
    for (int tile = 0; tile < KCHUNK / TK; ++tile) {
        const int j0 = j_base + tile * TK;
        __syncthreads();   // protect LDS from previous tile's readers
        // stage K/V tile (64 rows x 64 cols each) with row replacement,
        // write-through to the output caches.
#pragma unroll
        for (int p = 0; p < 4; ++p) {
            int idx = t + p * 256;                 // 0..1023
            int row = idx >> 4, c4 = idx & 15;
            long long j = j0 + row;
            int src = rowmap[j];
            const float* kb; const float* vb;
            if (src >= 0) { kb = knew + (long long)src * NSTATE; vb = vnew + (long long)src * NSTATE; }
            else          { kb = kci + j * NSTATE;               vb = vci + j * NSTATE; }
            float4 k4 = *(const float4*)(kb + h * D + c4 * 4);
            float4 v4 = *(const float4*)(vb + h * D + c4 * 4);
            *(float4*)(kc + j * NSTATE + h * D + c4 * 4) = k4;
            *(float4*)(vc + j * NSTATE + h * D + c4 * 4) = v4;
            ks_[c4 * 4 + 0][row] = k4.x; ks_[c4 * 4 + 1][row] = k4.y;
            ks_[c4 * 4 + 2][row] = k4.z; ks_[c4 * 4 + 3][row] = k4.w;
            *(float4*)&vs[row][c4 * 4] = v4;
        }
        __syncthreads();

        // QK^T: 4q x 2k per thread
        float s[4][2] = {};
#pragma unroll 8
        for (int d = 0; d < D; ++d) {
            float4 qv = *(const float4*)&qs[d][qt * 4];
            float2 kv = *(const float2*)&ks_[d][kt * 2];
            s[0][0] += qv.x * kv.x; s[0][1] += qv.x * kv.y;
            s[1][0] += qv.y * kv.x; s[1][1] += qv.y * kv.y;
            s[2][0] += qv.z * kv.x; s[2][1] += qv.z * kv.y;
            s[3][0] += qv.w * kv.x; s[3][1] += qv.w * kv.y;
        }
        // + mask
#pragma unroll
        for (int r = 0; r < 4; ++r) {
            int i = qt * 4 + r;
            float2 mv = *(const float2*)(mask + (long long)i * CACHE_N + j0 + kt * 2);
            s[r][0] += mv.x; s[r][1] += mv.y;
        }
        // per-query tile max
        float rmax[4];
#pragma unroll
        for (int r = 0; r < 4; ++r) rmax[r] = fmaxf(s[r][0], s[r][1]);
#pragma unroll
        for (int off = 16; off >= 1; off >>= 1)
#pragma unroll
            for (int r = 0; r < 4; ++r)
                rmax[r] = fmaxf(rmax[r], __shfl_xor(rmax[r], off, 64));
        if (kt == 0)
#pragma unroll
            for (int r = 0; r < 4; ++r) tmax[qt * 4 + r] = rmax[r];
        __syncthreads();
        if (t < Q) {
            float mo = m_s[t], mn = fmaxf(mo, tmax[t]);
            float a = __expf(mo - mn);
            m_s[t] = mn; alpha_s[t] = a; l_s[t] *= a;
        }
        __syncthreads();
        // p = exp(s - m_new); write P^T; per-query partial sums
        float pr[4][2], rsum[4];
#pragma unroll
        for (int r = 0; r < 4; ++r) {
            float mn = m_s[qt * 4 + r];
            pr[r][0] = __expf(s[r][0] - mn);
            pr[r][1] = __expf(s[r][1] - mn);
            rsum[r] = pr[r][0] + pr[r][1];
        }
#pragma unroll
        for (int c = 0; c < 2; ++c)
            *(float4*)&ps[kt * 2 + c][qt * 4] =
                make_float4(pr[0][c], pr[1][c], pr[2][c], pr[3][c]);
#pragma unroll
        for (int off = 16; off >= 1; off >>= 1)
#pragma unroll
            for (int r = 0; r < 4; ++r)
                rsum[r] += __shfl_xor(rsum[r], off, 64);
        if (kt == 0)
#pragma unroll
            for (int r = 0; r < 4; ++r) tsum[qt * 4 + r] = rsum[r];
        // rescale running output
        {
            float a0 = alpha_s[qt * 4 + 0], a1 = alpha_s[qt * 4 + 1];
            float a2 = alpha_s[qt * 4 + 2], a3 = alpha_s[qt * 4 + 3];
            oacc[0][0] *= a0; oacc[0][1] *= a0;
            oacc[1][0] *= a1; oacc[1][1] *= a1;
            oacc[2][0] *= a2; oacc[2][1] *= a2;
            oacc[3][0] *= a3; oacc[3][1] *= a3;
        }
        __syncthreads();
        if (t < Q) l_s[t] += tsum[t];
        // PV: 4q x 2d per thread
#pragma unroll 8
        for (int j = 0; j < TK; ++j) {
            float4 pv = *(const float4*)&ps[j][qt * 4];
            float2 vv = *(const float2*)&vs[j][dt * 2];
            oacc[0][0] += pv.x * vv.x; oacc[0][1] += pv.x * vv.y;
            oacc[1][0] += pv.y * vv.x; oacc[1][1] += pv.y * vv.y;
            oacc[2][0] += pv.z * vv.x; oacc[2][1] += pv.z * vv.y;
            oacc[3][0] += pv.w * vv.x; oacc[3][1] += pv.w * vv.y;
        }
    }
    __syncthreads();
    const int pb = (h * NSPLIT + sp) * Q;
    if (t < Q) { mpart[pb + t] = m_s[t]; lpart[pb + t] = l_s[t]; }
#pragma unroll
    for (int r = 0; r < 4; ++r) {
        int i = qt * 4 + r;
        __hip_bfloat16 hx = __float2bfloat16(oacc[r][0]);
        __hip_bfloat16 hy = __float2bfloat16(oacc[r][1]);
        ushort2 u = make_ushort2(*(unsigned short*)&hx, *(unsigned short*)&hy);
        *(ushort2*)((unsigned short*)opart + (size_t)(pb + i) * D + dt * 2) = u;
    }
}

// Combine split partials -> attention output [32,1280]
__global__ __launch_bounds__(64)
void attn_combine(const float* __restrict__ mpart, const float* __restrict__ lpart,
                  const __hip_bfloat16* __restrict__ opart, float* __restrict__ oattn) {
    const int i = blockIdx.x;   // query
    const int h = blockIdx.y;   // head
    const int d = threadIdx.x;  // dim
    float m[NSPLIT];
    float gm = -1e30f;
#pragma unroll
    for (int s = 0; s < NSPLIT; ++s) {
        m[s] = mpart[(h * NSPLIT + s) * Q + i];
        gm = fmaxf(gm, m[s]);
    }
    float l = 0.f, o = 0.f;
#pragma unroll
    for (int s = 0; s < NSPLIT; ++s) {
        float w = __expf(m[s] - gm);
        l += lpart[(h * NSPLIT + s) * Q + i] * w;
        o += __bfloat162float(opart[(size_t)((h * NSPLIT + s) * Q + i) * D + d]) * w;
    }
    oattn[i * NSTATE + h * D + d] = o / l;
}

// ---------------------------------------------------------------------------
extern "C" void kernel_launch(void* const* d_in, const int* in_sizes, int n_in,
                              void* d_out, int out_size, void* d_ws, size_t ws_size,
                              hipStream_t stream) {
    const float* x    = (const float*)d_in[0];
    const float* kci  = (const float*)d_in[1];
    const float* vci  = (const float*)d_in[2];
    const int*   pos  = (const int*)d_in[3];
    const float* mask = (const float*)d_in[4];
    const float* Wq   = (const float*)d_in[5];
    const float* bq   = (const float*)d_in[6];
    const float* Wk   = (const float*)d_in[7];
    const float* Wv   = (const float*)d_in[8];
    const float* bv   = (const float*)d_in[9];
    const float* Wout = (const float*)d_in[10];
    const float* bout = (const float*)d_in[11];

    float* out  = (float*)d_out;                 // [32*1280]
    float* kc   = out + 40960;                   // [16384*1280]
    float* vc   = kc + CACHE_N * NSTATE;

    // workspace layout (float offsets); total 3,342,336 B — within the
    // footprint proven safe in round 1 (3,358,720 B).
    float* ws      = (float*)d_ws;
    float* kws     = ws;                          // 40960
    float* vws     = ws + 40960;                  // 40960
    float* qws     = ws + 81920;                  // 40960 (reused as oattn)
    float* mpart   = ws + 122880;                 // 20480
    float* lpart   = ws + 143360;                 // 20480
    int*   rowmap  = (int*)(ws + 163840);         // 16384 ints
    __hip_bfloat16* opart = (__hip_bfloat16*)(ws + 180224);  // 1,310,720 bf16
    float* oattn   = qws;

    // zero atomic-accumulation targets; rowmap to -1
    hipMemsetAsync(ws, 0, 3 * 40960 * sizeof(float), stream);
    hipMemsetAsync(out, 0, 40960 * sizeof(float), stream);
    hipMemsetAsync(rowmap, 0xFF, CACHE_N * sizeof(int), stream);

    build_rowmap<<<1, 64, 0, stream>>>(pos, rowmap);

    // 1. q/k/v projections
    gemm_qkv<<<dim3(NSTATE / 64, 4, 3), 256, 0, stream>>>(x, Wq, bq, Wk, Wv, bv, qws, kws, vws);

    // 2. fused cache-update + attention partials
    attn_fused<<<dim3(NSPLIT, H), 256, 0, stream>>>(qws, kci, vci, kws, vws, rowmap, mask,
                                                    kc, vc, mpart, lpart, opart);

    // 3. combine splits
    attn_combine<<<dim3(Q, H), 64, 0, stream>>>(mpart, lpart, opart, oattn);

    // 4. output projection
    gemm_one<<<dim3(NSTATE / 64, 4), 256, 0, stream>>>(oattn, Wout, bout, out);
}